// Round 3
// baseline (15.095 us; speedup 1.0000x reference)
//
#include <hip/hip_runtime.h>

#define RWIN 5
#define TMAX 8192

// Kernel 1: one 128-thread block (2 waves) per (row, window) task.
// Fine granularity -> HW block dispatcher load-balances the ragged lengths.
// Writes raw max/min per window into ws[row*10 + {win, 5+win}].
__global__ __launch_bounds__(128) void window_minmax_kernel(
    const float* __restrict__ in, const int* __restrict__ lengths,
    float* __restrict__ ws)
{
    __shared__ float sm[4];

    const int task = blockIdx.x;
    const int row  = task / RWIN;
    const int win  = task % RWIN;
    const int tid  = threadIdx.x;     // 0..127
    const int w    = tid >> 6;        // wave 0/1
    const int lane = tid & 63;

    const int L = lengths[row];
    const float* rowp = in + (size_t)row * TMAX;

    const int s = (win * L) / RWIN;                      // start (incl)
    const int e = ((win + 1) * L + (RWIN - 1)) / RWIN;   // end (excl), >= s+1

    float mx = -__builtin_inff();
    float mn =  __builtin_inff();

    // Aligned float4 body with scalar head/tail, striped across all 128 threads.
    int s4 = (s + 3) & ~3; if (s4 > e)  s4 = e;
    int e4 = e & ~3;       if (e4 < s4) e4 = s4;

    for (int t = s + tid; t < s4; t += 128) {            // head (<4 elems)
        const float x = rowp[t];
        mx = fmaxf(mx, x); mn = fminf(mn, x);
    }
    for (int t = s4 + tid * 4; t < e4; t += 128 * 4) {   // vector body
        const float4 v = *reinterpret_cast<const float4*>(rowp + t);
        mx = fmaxf(mx, fmaxf(fmaxf(v.x, v.y), fmaxf(v.z, v.w)));
        mn = fminf(mn, fminf(fminf(v.x, v.y), fminf(v.z, v.w)));
    }
    for (int t = e4 + tid; t < e; t += 128) {            // tail (<4 elems)
        const float x = rowp[t];
        mx = fmaxf(mx, x); mn = fminf(mn, x);
    }

    // Per-wave butterfly, then cross-wave combine via LDS.
    #pragma unroll
    for (int off = 1; off < 64; off <<= 1) {
        mx = fmaxf(mx, __shfl_xor(mx, off));
        mn = fminf(mn, __shfl_xor(mn, off));
    }
    if (lane == 0) { sm[w] = mx; sm[2 + w] = mn; }
    __syncthreads();
    if (tid == 0) {
        ws[row * (2 * RWIN) + win]        = fmaxf(sm[0], sm[1]);
        ws[row * (2 * RWIN) + RWIN + win] = fminf(sm[2], sm[3]);
    }
}

// Kernel 2: one thread per output value; 10-element rank sort (stable by index).
__global__ __launch_bounds__(256) void rank_sort_kernel(
    const float* __restrict__ ws, float* __restrict__ out, int n)
{
    const int g = blockIdx.x * 256 + threadIdx.x;
    if (g >= n) return;
    const int row = g / (2 * RWIN);
    const int j   = g % (2 * RWIN);
    const float* base = ws + row * (2 * RWIN);
    const float v = base[j];
    int pos = 0;
    #pragma unroll
    for (int k = 0; k < 2 * RWIN; ++k) {
        const float vk = base[k];
        pos += (int)((vk < v) | ((vk == v) & (k < j)));
    }
    out[row * (2 * RWIN) + pos] = v;
}

extern "C" void kernel_launch(void* const* d_in, const int* in_sizes, int n_in,
                              void* d_out, int out_size, void* d_ws, size_t ws_size,
                              hipStream_t stream) {
    const float* in      = (const float*)d_in[0];
    const int*   lengths = (const int*)d_in[1];
    float*       out     = (float*)d_out;
    float*       ws      = (float*)d_ws;
    const int B = in_sizes[1];   // 2048 rows

    window_minmax_kernel<<<B * RWIN, 128, 0, stream>>>(in, lengths, ws);

    const int n = B * 2 * RWIN;
    rank_sort_kernel<<<(n + 255) / 256, 256, 0, stream>>>(ws, out, n);
}